// Round 3
// baseline (89.943 us; speedup 1.0000x reference)
//
#include <hip/hip_runtime.h>
#include <hip/hip_bf16.h>

// Shapes (fixed by the reference): B=1, M=N=256, O=P=12, C=128, D=32
#define N_ 256
#define M_ 256
#define O_ 12
#define C_ 128
#define D_ 32
#define S2 16     // K-splits of the spatial GEMM (16 n-rows per block)

typedef __attribute__((ext_vector_type(8))) short short8;   // 8 x bf16
typedef __attribute__((ext_vector_type(4))) float floatx4;  // MFMA acc

static __device__ __forceinline__ short2 pk2(float a, float b) {
    // compiles to v_cvt_pk_bf16_f32 (RNE)
    union { __hip_bfloat162 h; short2 s; } u;
    u.h = __float22bfloat162_rn(make_float2(a, b));
    return u.s;
}

static __device__ __forceinline__ short f2bf(float f) {
    unsigned u = __float_as_uint(f);
    unsigned r = u + 0x7FFFu + ((u >> 16) & 1u);  // RNE
    return (short)(r >> 16);
}

// ---- fused prep: g[o][n][c][d] = bf16(x[n,o,c]*mask[n]*Ws[d,c])
//      and       rk[p,o,c] = sum_d fkb[p,o,d]*Wr[d,c]
__global__ __launch_bounds__(256) void prep_kernel(
    const float* __restrict__ x, const float* __restrict__ mask,
    const float* __restrict__ Ws, const float* __restrict__ fkb,
    const float* __restrict__ Wr, short* __restrict__ g,
    float* __restrict__ rk)
{
    const int b = blockIdx.x;
    if (b < N_ * O_) {
        const int n = b / O_;
        const int o = b % O_;
        const int t = threadIdx.x;
        const int c  = t >> 1;
        const int dh = (t & 1) * 16;
        const float xm = x[(n * O_ + o) * C_ + c] * mask[n];
        short8 w0, w1;
#pragma unroll
        for (int i = 0; i < 8; ++i) w0[i] = f2bf(xm * Ws[(dh + i) * C_ + c]);
#pragma unroll
        for (int i = 0; i < 8; ++i) w1[i] = f2bf(xm * Ws[(dh + 8 + i) * C_ + c]);
        short* gp = g + (((size_t)(o * N_ + n)) * C_ + c) * D_ + dh;
        *reinterpret_cast<short8*>(gp)     = w0;
        *reinterpret_cast<short8*>(gp + 8) = w1;
    } else {
        const int idx = (b - N_ * O_) * 256 + threadIdx.x;  // 0..18431
        const int c  = idx & (C_ - 1);
        const int po = idx >> 7;
        const float* f = fkb + po * D_;
        float acc = 0.f;
#pragma unroll
        for (int d = 0; d < D_; ++d) acc = fmaf(f[d], Wr[d * C_ + c], acc);
        rk[idx] = acc;
    }
}

// ---- spatial GEMM, barrier-free: part[sck][m][o][c]
// Per o: y1[m,c] = sum_{(n,d)} kb[m,n,o,d]*g[o,n,c,d].
// Block = 4 waves; wave owns 16 m-rows x 128 c. A and B direct from global.
__global__ __launch_bounds__(256, 4) void spatial2_kernel(
    const float* __restrict__ kb, const short* __restrict__ g,
    float* __restrict__ part)
{
    const int mt   = blockIdx.x;   // 0..3
    const int o    = blockIdx.y;   // 0..11
    const int sck  = blockIdx.z;   // 0..S2-1
    const int lane = threadIdx.x & 63;
    const int wave = threadIdx.x >> 6;
    const int l15  = lane & 15;
    const int lk   = lane >> 4;    // k-group: 8 consecutive d
    const int d0   = lk * 8;
    const int m0   = mt * 64 + wave * 16;

    // A: kb[m0+l15][n][o][d0..d0+8)  (contiguous fp32)
    const float* ka = kb + (size_t)(m0 + l15) * (N_ * O_ * D_) + o * D_ + d0;
    // B: g[o][n][cg*16+l15][d0..d0+8)  (contiguous bf16)
    const short* gbase = g + (size_t)o * (N_ * C_ * D_) + (size_t)l15 * D_ + d0;

    floatx4 acc[8];
#pragma unroll
    for (int cg = 0; cg < 8; ++cg)
#pragma unroll
        for (int q = 0; q < 4; ++q) acc[cg][q] = 0.f;

    const int n0 = sck * (N_ / S2);
#pragma unroll 2
    for (int i = 0; i < N_ / S2; ++i) {
        const int n = n0 + i;
        const float* ap = ka + (size_t)n * (O_ * D_);
        const floatx4 af0 = *reinterpret_cast<const floatx4*>(ap);
        const floatx4 af1 = *reinterpret_cast<const floatx4*>(ap + 4);
        const short* gn = gbase + (size_t)n * (C_ * D_);
        short8 bfr[8];
#pragma unroll
        for (int cg = 0; cg < 8; ++cg)
            bfr[cg] = *reinterpret_cast<const short8*>(gn + cg * 16 * D_);
        union { short8 v; short2 p[4]; } au;
        au.p[0] = pk2(af0[0], af0[1]);
        au.p[1] = pk2(af0[2], af0[3]);
        au.p[2] = pk2(af1[0], af1[1]);
        au.p[3] = pk2(af1[2], af1[3]);
#pragma unroll
        for (int cg = 0; cg < 8; ++cg)
            acc[cg] = __builtin_amdgcn_mfma_f32_16x16x32_bf16(au.v, bfr[cg], acc[cg], 0, 0, 0);
    }

    // C/D layout: col = lane&15, row = (lane>>4)*4 + reg  [verified round 2]
#pragma unroll
    for (int cg = 0; cg < 8; ++cg) {
        const int c = cg * 16 + l15;
#pragma unroll
        for (int j = 0; j < 4; ++j) {
            const int m = m0 + lk * 4 + j;
            part[(((size_t)sck * M_ + m) * O_ + o) * C_ + c] = acc[cg][j];
        }
    }
}

// ---- out[m,p,c] = (sum_o (sum_s part[s,m,o,c]) * rk[p,o,c])/12 + bias[c]
__global__ __launch_bounds__(256) void fiber2_kernel(
    const float* __restrict__ part, const float* __restrict__ rkv,
    const float* __restrict__ bias, float* __restrict__ out)
{
    const int m = blockIdx.x;
    const int t = threadIdx.x;
    const int c = t & 127;
    const int half = t >> 7;
    float y1v[O_];
#pragma unroll
    for (int o = 0; o < O_; ++o) {
        float a = 0.f;
#pragma unroll
        for (int s = 0; s < S2; ++s)
            a += part[(((size_t)s * M_ + m) * O_ + o) * C_ + c];
        y1v[o] = a;
    }
#pragma unroll
    for (int pp = 0; pp < O_ / 2; ++pp) {
        const int p = half * (O_ / 2) + pp;
        float a = 0.f;
#pragma unroll
        for (int o = 0; o < O_; ++o)
            a = fmaf(y1v[o], rkv[(p * O_ + o) * C_ + c], a);
        out[((size_t)m * O_ + p) * C_ + c] = a * (1.f / 12.f) + bias[c];
    }
}

// ---------------- fallback (round-1) path, used only if ws is small ------
__global__ __launch_bounds__(256) void spatial_old_kernel(
    const float* __restrict__ x, const float* __restrict__ kb,
    const float* __restrict__ mask, const float* __restrict__ Ws,
    float* __restrict__ y1)
{
    const int bid = blockIdx.x;
    const int m = bid / O_, o = bid % O_;
    const int tid = threadIdx.x;
    const int h = tid >> 7, c = tid & (C_ - 1);
    __shared__ float kbs[2][8][D_];
    __shared__ float msk[N_];
    __shared__ float Ts[2][D_][C_];
    msk[tid] = mask[tid];
    float T[D_];
#pragma unroll
    for (int d = 0; d < D_; ++d) T[d] = 0.f;
    const float* kb_mo = kb + (size_t)m * (N_ * O_ * D_) + o * D_;
    const int j_ld = c >> 4, d_ld = (c & 15) * 2;
    for (int chunk = 0; chunk < 16; ++chunk) {
        const int n0 = h * 128 + chunk * 8;
        __syncthreads();
        float2 v = *reinterpret_cast<const float2*>(
            kb_mo + (size_t)(n0 + j_ld) * (O_ * D_) + d_ld);
        kbs[h][j_ld][d_ld] = v.x;
        kbs[h][j_ld][d_ld + 1] = v.y;
        __syncthreads();
#pragma unroll
        for (int j = 0; j < 8; ++j) {
            const int n = n0 + j;
            const float xv = x[(n * O_ + o) * C_ + c] * msk[n];
#pragma unroll
            for (int d = 0; d < D_; ++d) T[d] = fmaf(kbs[h][j][d], xv, T[d]);
        }
    }
#pragma unroll
    for (int d = 0; d < D_; ++d) Ts[h][d][c] = T[d];
    __syncthreads();
    if (h == 0) {
        float a = 0.f;
#pragma unroll
        for (int d = 0; d < D_; ++d)
            a = fmaf(Ts[0][d][c] + Ts[1][d][c], Ws[d * C_ + c], a);
        y1[((size_t)m * O_ + o) * C_ + c] = a;
    }
}

__global__ __launch_bounds__(256) void fiber_old_kernel(
    const float* __restrict__ y1, const float* __restrict__ rkv,
    const float* __restrict__ bias, float* __restrict__ out)
{
    int idx = blockIdx.x * 256 + threadIdx.x;
    if (idx >= M_ * O_ * C_) return;
    int c = idx & (C_ - 1);
    int p = (idx >> 7) % O_;
    int m = idx / (O_ * C_);
    float a = 0.f;
#pragma unroll
    for (int o = 0; o < O_; ++o)
        a = fmaf(y1[(m * O_ + o) * C_ + c], rkv[(p * O_ + o) * C_ + c], a);
    out[idx] = a * (1.0f / 12.0f) + bias[c];
}

__global__ __launch_bounds__(256) void rot_proj_kernel(
    const float* __restrict__ fkb, const float* __restrict__ Wr,
    float* __restrict__ rk)
{
    int idx = blockIdx.x * 256 + threadIdx.x;
    if (idx >= O_ * O_ * C_) return;
    int c  = idx & (C_ - 1);
    int po = idx >> 7;
    const float* f = fkb + po * D_;
    float acc = 0.f;
#pragma unroll
    for (int d = 0; d < D_; ++d) acc = fmaf(f[d], Wr[d * C_ + c], acc);
    rk[idx] = acc;
}

extern "C" void kernel_launch(void* const* d_in, const int* in_sizes, int n_in,
                              void* d_out, int out_size, void* d_ws, size_t ws_size,
                              hipStream_t stream)
{
    const float* x    = (const float*)d_in[0];  // (1,256,12,128)
    const float* kb   = (const float*)d_in[1];  // (1,256,256,12,32)
    const float* fkb  = (const float*)d_in[2];  // (12,12,32)
    const float* mask = (const float*)d_in[3];  // (1,256)
    const float* Wsp  = (const float*)d_in[4];  // (32,128)
    const float* Wrt  = (const float*)d_in[5];  // (32,128)
    const float* bias = (const float*)d_in[6];  // (128,)
    float* out = (float*)d_out;                 // (1,256,12,128)

    const size_t RK_F   = (size_t)O_ * O_ * C_;            // 18432 floats
    const size_t PART_F = (size_t)S2 * M_ * O_ * C_;       // 6291456 floats
    const size_t G_E    = (size_t)O_ * N_ * C_ * D_;       // 12582912 bf16
    const size_t need   = (RK_F + PART_F) * 4 + G_E * 2;   // ~50.5 MB

    float* rk = (float*)d_ws;

    if (ws_size >= need) {
        float* part = rk + RK_F;
        short* g    = (short*)(part + PART_F);
        prep_kernel<<<N_ * O_ + (O_ * O_ * C_) / 256, 256, 0, stream>>>(
            x, mask, Wsp, fkb, Wrt, g, rk);
        spatial2_kernel<<<dim3(M_ / 64, O_, S2), 256, 0, stream>>>(kb, g, part);
        fiber2_kernel<<<M_, 256, 0, stream>>>(part, rk, bias, out);
    } else {
        float* y1 = rk + RK_F;
        rot_proj_kernel<<<(O_ * O_ * C_ + 255) / 256, 256, 0, stream>>>(fkb, Wrt, rk);
        spatial_old_kernel<<<M_ * O_, 256, 0, stream>>>(x, kb, mask, Wsp, y1);
        fiber_old_kernel<<<(M_ * O_ * C_ + 255) / 256, 256, 0, stream>>>(y1, rk, bias, out);
    }
}

// Round 4
// 78.749 us; speedup vs baseline: 1.1422x; 1.1422x over previous
//
#include <hip/hip_runtime.h>
#include <hip/hip_bf16.h>

// Shapes (fixed by the reference): B=1, M=N=256, O=P=12, C=128, D=32
#define N_ 256
#define M_ 256
#define O_ 12
#define C_ 128
#define D_ 32
#define S2 16     // K-splits of the spatial GEMM (16 n-rows per block)

typedef __attribute__((ext_vector_type(8))) short short8;   // 8 x bf16
typedef __attribute__((ext_vector_type(4))) float floatx4;  // MFMA acc

static __device__ __forceinline__ short2 pk2(float a, float b) {
    // compiles to v_cvt_pk_bf16_f32 (RNE)
    union { __hip_bfloat162 h; short2 s; } u;
    u.h = __float22bfloat162_rn(make_float2(a, b));
    return u.s;
}

static __device__ __forceinline__ short f2bf(float f) {
    unsigned u = __float_as_uint(f);
    unsigned r = u + 0x7FFFu + ((u >> 16) & 1u);  // RNE
    return (short)(r >> 16);
}

// ---- fused prep: g[o][n][c][d] = bf16(x[n,o,c]*mask[n]*Ws[d,c])
//      and       rk[p,o,c] = sum_d fkb[p,o,d]*Wr[d,c]
__global__ __launch_bounds__(256) void prep_kernel(
    const float* __restrict__ x, const float* __restrict__ mask,
    const float* __restrict__ Ws, const float* __restrict__ fkb,
    const float* __restrict__ Wr, short* __restrict__ g,
    float* __restrict__ rk)
{
    const int b = blockIdx.x;
    if (b < N_ * O_) {
        const int n = b / O_;
        const int o = b % O_;
        const int t = threadIdx.x;
        const int c  = t >> 1;
        const int dh = (t & 1) * 16;
        const float xm = x[(n * O_ + o) * C_ + c] * mask[n];
        short8 w0, w1;
#pragma unroll
        for (int i = 0; i < 8; ++i) w0[i] = f2bf(xm * Ws[(dh + i) * C_ + c]);
#pragma unroll
        for (int i = 0; i < 8; ++i) w1[i] = f2bf(xm * Ws[(dh + 8 + i) * C_ + c]);
        short* gp = g + (((size_t)(o * N_ + n)) * C_ + c) * D_ + dh;
        *reinterpret_cast<short8*>(gp)     = w0;
        *reinterpret_cast<short8*>(gp + 8) = w1;
    } else {
        const int idx = (b - N_ * O_) * 256 + threadIdx.x;  // 0..18431
        const int c  = idx & (C_ - 1);
        const int po = idx >> 7;
        const float* f = fkb + po * D_;
        float acc = 0.f;
#pragma unroll
        for (int d = 0; d < D_; ++d) acc = fmaf(f[d], Wr[d * C_ + c], acc);
        rk[idx] = acc;
    }
}

// ---- spatial GEMM, barrier-free, depth-4 A prefetch: part[sck][m][o][c]
// Per o: y1[m,c] = sum_{(n,d)} kb[m,n,o,d]*g[o,n,c,d].
// Block = 4 waves; wave owns 16 m-rows x 128 c. A and B direct from global.
__global__ __launch_bounds__(256, 3) void spatial3_kernel(
    const float* __restrict__ kb, const short* __restrict__ g,
    float* __restrict__ part)
{
    const int mt   = blockIdx.x;   // 0..3
    const int o    = blockIdx.y;   // 0..11
    const int sck  = blockIdx.z;   // 0..S2-1
    const int lane = threadIdx.x & 63;
    const int wave = threadIdx.x >> 6;
    const int l15  = lane & 15;
    const int lk   = lane >> 4;    // k-group: 8 consecutive d
    const int d0   = lk * 8;
    const int m0   = mt * 64 + wave * 16;

    // A: kb[m0+l15][n][o][d0..d0+8)  (contiguous fp32)
    const float* ka = kb + (size_t)(m0 + l15) * (N_ * O_ * D_) + o * D_ + d0;
    // B: g[o][n][cg*16+l15][d0..d0+8)  (contiguous bf16)
    const short* gbase = g + (size_t)o * (N_ * C_ * D_) + (size_t)l15 * D_ + d0;

    floatx4 acc[8];
#pragma unroll
    for (int cg = 0; cg < 8; ++cg)
#pragma unroll
        for (int q = 0; q < 4; ++q) acc[cg][q] = 0.f;

    const int n0 = sck * (N_ / S2);

    // Rotating A buffers, depth 4 (named — no runtime indexing)
    floatx4 aA[2], aB[2], aC[2], aD[2];
#define LOADA(BUF, IDX) { \
    const float* p_ = ka + (size_t)(n0 + (IDX)) * (O_ * D_); \
    BUF[0] = *reinterpret_cast<const floatx4*>(p_); \
    BUF[1] = *reinterpret_cast<const floatx4*>(p_ + 4); }

    LOADA(aA, 0)
    LOADA(aB, 1)
    LOADA(aC, 2)

    // Step j: issue B(j); issue A(j+3) into NXT; cvt CUR; 8 MFMAs.
#define STEPX(J, CUR, NXT) { \
    const int jj = (J); \
    const short* gn_ = gbase + (size_t)(n0 + jj) * (C_ * D_); \
    short8 bfr[8]; \
    _Pragma("unroll") \
    for (int cg = 0; cg < 8; ++cg) \
        bfr[cg] = *reinterpret_cast<const short8*>(gn_ + cg * 16 * D_); \
    { const int jn_ = (jj + 3 <= 15) ? (jj + 3) : 15; \
      LOADA(NXT, jn_) } \
    union { short8 v; short2 p2[4]; } au_; \
    au_.p2[0] = pk2(CUR[0][0], CUR[0][1]); \
    au_.p2[1] = pk2(CUR[0][2], CUR[0][3]); \
    au_.p2[2] = pk2(CUR[1][0], CUR[1][1]); \
    au_.p2[3] = pk2(CUR[1][2], CUR[1][3]); \
    _Pragma("unroll") \
    for (int cg = 0; cg < 8; ++cg) \
        acc[cg] = __builtin_amdgcn_mfma_f32_16x16x32_bf16(au_.v, bfr[cg], acc[cg], 0, 0, 0); }

    for (int it = 0; it < 4; ++it) {
        const int j0 = it * 4;
        STEPX(j0 + 0, aA, aD)
        STEPX(j0 + 1, aB, aA)
        STEPX(j0 + 2, aC, aB)
        STEPX(j0 + 3, aD, aC)
    }
#undef STEPX
#undef LOADA

    // C/D layout: col = lane&15, row = (lane>>4)*4 + reg  [verified round 2]
#pragma unroll
    for (int cg = 0; cg < 8; ++cg) {
        const int c = cg * 16 + l15;
#pragma unroll
        for (int j = 0; j < 4; ++j) {
            const int m = m0 + lk * 4 + j;
            part[(((size_t)sck * M_ + m) * O_ + o) * C_ + c] = acc[cg][j];
        }
    }
}

// ---- out[m,p,c] = (sum_o (sum_s part[s,m,o,c]) * rk[p,o,c])/12 + bias[c]
__global__ __launch_bounds__(256) void fiber2_kernel(
    const float* __restrict__ part, const float* __restrict__ rkv,
    const float* __restrict__ bias, float* __restrict__ out)
{
    const int m = blockIdx.x;
    const int t = threadIdx.x;
    const int c = t & 127;
    const int half = t >> 7;
    float y1v[O_];
#pragma unroll
    for (int o = 0; o < O_; ++o) {
        float a = 0.f;
#pragma unroll
        for (int s = 0; s < S2; ++s)
            a += part[(((size_t)s * M_ + m) * O_ + o) * C_ + c];
        y1v[o] = a;
    }
#pragma unroll
    for (int pp = 0; pp < O_ / 2; ++pp) {
        const int p = half * (O_ / 2) + pp;
        float a = 0.f;
#pragma unroll
        for (int o = 0; o < O_; ++o)
            a = fmaf(y1v[o], rkv[(p * O_ + o) * C_ + c], a);
        out[((size_t)m * O_ + p) * C_ + c] = a * (1.f / 12.f) + bias[c];
    }
}

// ---------------- fallback (round-1) path, used only if ws is small ------
__global__ __launch_bounds__(256) void spatial_old_kernel(
    const float* __restrict__ x, const float* __restrict__ kb,
    const float* __restrict__ mask, const float* __restrict__ Ws,
    float* __restrict__ y1)
{
    const int bid = blockIdx.x;
    const int m = bid / O_, o = bid % O_;
    const int tid = threadIdx.x;
    const int h = tid >> 7, c = tid & (C_ - 1);
    __shared__ float kbs[2][8][D_];
    __shared__ float msk[N_];
    __shared__ float Ts[2][D_][C_];
    msk[tid] = mask[tid];
    float T[D_];
#pragma unroll
    for (int d = 0; d < D_; ++d) T[d] = 0.f;
    const float* kb_mo = kb + (size_t)m * (N_ * O_ * D_) + o * D_;
    const int j_ld = c >> 4, d_ld = (c & 15) * 2;
    for (int chunk = 0; chunk < 16; ++chunk) {
        const int n0 = h * 128 + chunk * 8;
        __syncthreads();
        float2 v = *reinterpret_cast<const float2*>(
            kb_mo + (size_t)(n0 + j_ld) * (O_ * D_) + d_ld);
        kbs[h][j_ld][d_ld] = v.x;
        kbs[h][j_ld][d_ld + 1] = v.y;
        __syncthreads();
#pragma unroll
        for (int j = 0; j < 8; ++j) {
            const int n = n0 + j;
            const float xv = x[(n * O_ + o) * C_ + c] * msk[n];
#pragma unroll
            for (int d = 0; d < D_; ++d) T[d] = fmaf(kbs[h][j][d], xv, T[d]);
        }
    }
#pragma unroll
    for (int d = 0; d < D_; ++d) Ts[h][d][c] = T[d];
    __syncthreads();
    if (h == 0) {
        float a = 0.f;
#pragma unroll
        for (int d = 0; d < D_; ++d)
            a = fmaf(Ts[0][d][c] + Ts[1][d][c], Ws[d * C_ + c], a);
        y1[((size_t)m * O_ + o) * C_ + c] = a;
    }
}

__global__ __launch_bounds__(256) void fiber_old_kernel(
    const float* __restrict__ y1, const float* __restrict__ rkv,
    const float* __restrict__ bias, float* __restrict__ out)
{
    int idx = blockIdx.x * 256 + threadIdx.x;
    if (idx >= M_ * O_ * C_) return;
    int c = idx & (C_ - 1);
    int p = (idx >> 7) % O_;
    int m = idx / (O_ * C_);
    float a = 0.f;
#pragma unroll
    for (int o = 0; o < O_; ++o)
        a = fmaf(y1[(m * O_ + o) * C_ + c], rkv[(p * O_ + o) * C_ + c], a);
    out[idx] = a * (1.0f / 12.0f) + bias[c];
}

__global__ __launch_bounds__(256) void rot_proj_kernel(
    const float* __restrict__ fkb, const float* __restrict__ Wr,
    float* __restrict__ rk)
{
    int idx = blockIdx.x * 256 + threadIdx.x;
    if (idx >= O_ * O_ * C_) return;
    int c  = idx & (C_ - 1);
    int po = idx >> 7;
    const float* f = fkb + po * D_;
    float acc = 0.f;
#pragma unroll
    for (int d = 0; d < D_; ++d) acc = fmaf(f[d], Wr[d * C_ + c], acc);
    rk[idx] = acc;
}

extern "C" void kernel_launch(void* const* d_in, const int* in_sizes, int n_in,
                              void* d_out, int out_size, void* d_ws, size_t ws_size,
                              hipStream_t stream)
{
    const float* x    = (const float*)d_in[0];  // (1,256,12,128)
    const float* kb   = (const float*)d_in[1];  // (1,256,256,12,32)
    const float* fkb  = (const float*)d_in[2];  // (12,12,32)
    const float* mask = (const float*)d_in[3];  // (1,256)
    const float* Wsp  = (const float*)d_in[4];  // (32,128)
    const float* Wrt  = (const float*)d_in[5];  // (32,128)
    const float* bias = (const float*)d_in[6];  // (128,)
    float* out = (float*)d_out;                 // (1,256,12,128)

    const size_t RK_F   = (size_t)O_ * O_ * C_;            // 18432 floats
    const size_t PART_F = (size_t)S2 * M_ * O_ * C_;       // 6291456 floats
    const size_t G_E    = (size_t)O_ * N_ * C_ * D_;       // 12582912 bf16
    const size_t need   = (RK_F + PART_F) * 4 + G_E * 2;   // ~50.5 MB

    float* rk = (float*)d_ws;

    if (ws_size >= need) {
        float* part = rk + RK_F;
        short* g    = (short*)(part + PART_F);
        prep_kernel<<<N_ * O_ + (O_ * O_ * C_) / 256, 256, 0, stream>>>(
            x, mask, Wsp, fkb, Wrt, g, rk);
        spatial3_kernel<<<dim3(M_ / 64, O_, S2), 256, 0, stream>>>(kb, g, part);
        fiber2_kernel<<<M_, 256, 0, stream>>>(part, rk, bias, out);
    } else {
        float* y1 = rk + RK_F;
        rot_proj_kernel<<<(O_ * O_ * C_ + 255) / 256, 256, 0, stream>>>(fkb, Wrt, rk);
        spatial_old_kernel<<<M_ * O_, 256, 0, stream>>>(x, kb, mask, Wsp, y1);
        fiber_old_kernel<<<(M_ * O_ * C_ + 255) / 256, 256, 0, stream>>>(y1, rk, bias, out);
    }
}

// Round 5
// 72.281 us; speedup vs baseline: 1.2444x; 1.0895x over previous
//
#include <hip/hip_runtime.h>
#include <hip/hip_bf16.h>

// Shapes (fixed by the reference): B=1, M=N=256, O=P=12, C=128, D=32
#define N_ 256
#define M_ 256
#define O_ 12
#define C_ 128
#define D_ 32
#define S2 16     // K-splits of the spatial GEMM (16 n-rows per block)

typedef __attribute__((ext_vector_type(8))) short short8;   // 8 x bf16
typedef __attribute__((ext_vector_type(4))) float floatx4;  // MFMA acc

// async global->LDS DMA, 16B per lane: LDS dst = uniform base + lane*16,
// global src is PER-LANE (m173).
#define GLD16(GSRC, LDST) \
    __builtin_amdgcn_global_load_lds( \
        (const __attribute__((address_space(1))) void*)(GSRC), \
        (__attribute__((address_space(3))) void*)(LDST), 16, 0, 0)

static __device__ __forceinline__ short2 pk2(float a, float b) {
    union { __hip_bfloat162 h; short2 s; } u;
    u.h = __float22bfloat162_rn(make_float2(a, b));  // v_cvt_pk_bf16_f32
    return u.s;
}

static __device__ __forceinline__ short f2bf(float f) {
    unsigned u = __float_as_uint(f);
    unsigned r = u + 0x7FFFu + ((u >> 16) & 1u);  // RNE
    return (short)(r >> 16);
}

// ---- fused prep: g[o][n][c][d] = bf16(x[n,o,c]*mask[n]*Ws[d,c])
//      and       rk[p,o,c] = sum_d fkb[p,o,d]*Wr[d,c]
__global__ __launch_bounds__(256) void prep_kernel(
    const float* __restrict__ x, const float* __restrict__ mask,
    const float* __restrict__ Ws, const float* __restrict__ fkb,
    const float* __restrict__ Wr, short* __restrict__ g,
    float* __restrict__ rk)
{
    const int b = blockIdx.x;
    if (b < N_ * O_) {
        const int n = b / O_;
        const int o = b % O_;
        const int t = threadIdx.x;
        const int c  = t >> 1;
        const int dh = (t & 1) * 16;
        const float xm = x[(n * O_ + o) * C_ + c] * mask[n];
        short8 w0, w1;
#pragma unroll
        for (int i = 0; i < 8; ++i) w0[i] = f2bf(xm * Ws[(dh + i) * C_ + c]);
#pragma unroll
        for (int i = 0; i < 8; ++i) w1[i] = f2bf(xm * Ws[(dh + 8 + i) * C_ + c]);
        short* gp = g + (((size_t)(o * N_ + n)) * C_ + c) * D_ + dh;
        *reinterpret_cast<short8*>(gp)     = w0;
        *reinterpret_cast<short8*>(gp + 8) = w1;
    } else {
        const int idx = (b - N_ * O_) * 256 + threadIdx.x;  // 0..18431
        const int c  = idx & (C_ - 1);
        const int po = idx >> 7;
        const float* f = fkb + po * D_;
        float acc = 0.f;
#pragma unroll
        for (int d = 0; d < D_; ++d) acc = fmaf(f[d], Wr[d * C_ + c], acc);
        rk[idx] = acc;
    }
}

// ---- spatial GEMM with global_load_lds double-buffered staging ----------
// Per o: y1[m,c] = sum_{(n,d)} kb[m,n,o,d]*g[o,n,c,d].
// Block: 64 m-rows x 128 c, 16 n (one n per step, BK=32). 4 waves, each
// owns 16 m-rows x 128 c (8 MFMAs/step). A and B staged via DMA to LDS.
//
// A LDS placement: slot(r,chunk16B) = r*8 + ((chunk + r) & 7)  -- rotate
// permutation applied on the DMA *source* address (LDS dst stays linear),
// read back with the same rotation => even bank spread.  B stays linear
// [c][d] (even spread already: slots (l15&1, lk)).
__global__ __launch_bounds__(256) void spatial4_kernel(
    const float* __restrict__ kb, const short* __restrict__ g,
    float* __restrict__ part)
{
    const int mt  = blockIdx.x;   // 0..3
    const int o   = blockIdx.y;   // 0..11
    const int sck = blockIdx.z;   // 0..15
    const int t    = threadIdx.x;
    const int lane = t & 63;
    const int wave = t >> 6;
    const int l15  = lane & 15;
    const int lk   = lane >> 4;
    const int m0   = mt * 64;
    const int n0   = sck * (N_ / S2);

    __shared__ __align__(16) float Abuf[2][64 * 32];   // 8 KB per buf
    __shared__ __align__(16) short Bbuf[2][128 * 32];  // 8 KB per buf

    // ---- staging constants (each wave issues 2 A + 2 B DMA instrs/step)
    const int iA0 = 2 * wave, iA1 = 2 * wave + 1;
    const int arow0 = 8 * iA0 + (lane >> 3);         // rows covered by instr
    const int arow1 = 8 * iA1 + (lane >> 3);
    const int achk  = ((lane & 7) - (lane >> 3)) & 7; // pre-rotated src chunk
    const float* kbA0 = kb + (size_t)(m0 + arow0) * (N_ * O_ * D_)
                           + (size_t)n0 * (O_ * D_) + o * D_ + achk * 4;
    const float* kbA1 = kb + (size_t)(m0 + arow1) * (N_ * O_ * D_)
                           + (size_t)n0 * (O_ * D_) + o * D_ + achk * 4;
    const short* gsl = g + (size_t)o * (N_ * C_ * D_)
                         + (size_t)n0 * (C_ * D_) + lane * 8;

#define STAGE(BUF, S) { \
    const size_t no_ = (size_t)(S) * (O_ * D_); \
    GLD16(kbA0 + no_, &Abuf[BUF][iA0 * 256]); \
    GLD16(kbA1 + no_, &Abuf[BUF][iA1 * 256]); \
    const short* gs_ = gsl + (size_t)(S) * (C_ * D_); \
    GLD16(gs_ + iA0 * 512, &Bbuf[BUF][iA0 * 512]); \
    GLD16(gs_ + iA1 * 512, &Bbuf[BUF][iA1 * 512]); }

    floatx4 acc[8];
#pragma unroll
    for (int cg = 0; cg < 8; ++cg)
#pragma unroll
        for (int q = 0; q < 4; ++q) acc[cg][q] = 0.f;

    const int rloc = wave * 16 + l15;            // A row this lane reads
    const int ja = (2 * lk + rloc) & 7;          // rotated chunk indices
    const int jb = (2 * lk + 1 + rloc) & 7;

    STAGE(0, 0);
    __syncthreads();   // vmcnt(0) drain: buf0 ready

#pragma unroll
    for (int s = 0; s < N_ / S2; ++s) {
        const int b = s & 1;
        if (s + 1 < N_ / S2) STAGE(b ^ 1, s + 1);   // issue next-step DMA

        const floatx4 a0 = *reinterpret_cast<const floatx4*>(
            &Abuf[b][rloc * 32 + ja * 4]);
        const floatx4 a1 = *reinterpret_cast<const floatx4*>(
            &Abuf[b][rloc * 32 + jb * 4]);
        union { short8 v; short2 p2[4]; } au;
        au.p2[0] = pk2(a0[0], a0[1]);
        au.p2[1] = pk2(a0[2], a0[3]);
        au.p2[2] = pk2(a1[0], a1[1]);
        au.p2[3] = pk2(a1[2], a1[3]);
#pragma unroll
        for (int cg = 0; cg < 8; ++cg) {
            const short8 bf = *reinterpret_cast<const short8*>(
                &Bbuf[b][(cg * 16 + l15) * 32 + lk * 8]);
            acc[cg] = __builtin_amdgcn_mfma_f32_16x16x32_bf16(au.v, bf, acc[cg], 0, 0, 0);
        }
        __syncthreads();  // readers done with buf b AND next buf's DMA drained
    }
#undef STAGE

    // C/D layout: col = lane&15, row = (lane>>4)*4 + reg  [verified round 2]
#pragma unroll
    for (int cg = 0; cg < 8; ++cg) {
        const int c = cg * 16 + l15;
#pragma unroll
        for (int j = 0; j < 4; ++j) {
            const int m = m0 + wave * 16 + lk * 4 + j;
            part[(((size_t)sck * M_ + m) * O_ + o) * C_ + c] = acc[cg][j];
        }
    }
}

// ---- out[m,p,c] = (sum_o (sum_s part[s,m,o,c]) * rk[p,o,c])/12 + bias[c]
__global__ __launch_bounds__(256) void fiber2_kernel(
    const float* __restrict__ part, const float* __restrict__ rkv,
    const float* __restrict__ bias, float* __restrict__ out)
{
    const int m = blockIdx.x;
    const int t = threadIdx.x;
    const int c = t & 127;
    const int half = t >> 7;
    float y1v[O_];
#pragma unroll
    for (int o = 0; o < O_; ++o) {
        float a = 0.f;
#pragma unroll
        for (int s = 0; s < S2; ++s)
            a += part[(((size_t)s * M_ + m) * O_ + o) * C_ + c];
        y1v[o] = a;
    }
#pragma unroll
    for (int pp = 0; pp < O_ / 2; ++pp) {
        const int p = half * (O_ / 2) + pp;
        float a = 0.f;
#pragma unroll
        for (int o = 0; o < O_; ++o)
            a = fmaf(y1v[o], rkv[(p * O_ + o) * C_ + c], a);
        out[((size_t)m * O_ + p) * C_ + c] = a * (1.f / 12.f) + bias[c];
    }
}

// ---------------- fallback (round-1) path, used only if ws is small ------
__global__ __launch_bounds__(256) void spatial_old_kernel(
    const float* __restrict__ x, const float* __restrict__ kb,
    const float* __restrict__ mask, const float* __restrict__ Ws,
    float* __restrict__ y1)
{
    const int bid = blockIdx.x;
    const int m = bid / O_, o = bid % O_;
    const int tid = threadIdx.x;
    const int h = tid >> 7, c = tid & (C_ - 1);
    __shared__ float kbs[2][8][D_];
    __shared__ float msk[N_];
    __shared__ float Ts[2][D_][C_];
    msk[tid] = mask[tid];
    float T[D_];
#pragma unroll
    for (int d = 0; d < D_; ++d) T[d] = 0.f;
    const float* kb_mo = kb + (size_t)m * (N_ * O_ * D_) + o * D_;
    const int j_ld = c >> 4, d_ld = (c & 15) * 2;
    for (int chunk = 0; chunk < 16; ++chunk) {
        const int n0 = h * 128 + chunk * 8;
        __syncthreads();
        float2 v = *reinterpret_cast<const float2*>(
            kb_mo + (size_t)(n0 + j_ld) * (O_ * D_) + d_ld);
        kbs[h][j_ld][d_ld] = v.x;
        kbs[h][j_ld][d_ld + 1] = v.y;
        __syncthreads();
#pragma unroll
        for (int j = 0; j < 8; ++j) {
            const int n = n0 + j;
            const float xv = x[(n * O_ + o) * C_ + c] * msk[n];
#pragma unroll
            for (int d = 0; d < D_; ++d) T[d] = fmaf(kbs[h][j][d], xv, T[d]);
        }
    }
#pragma unroll
    for (int d = 0; d < D_; ++d) Ts[h][d][c] = T[d];
    __syncthreads();
    if (h == 0) {
        float a = 0.f;
#pragma unroll
        for (int d = 0; d < D_; ++d)
            a = fmaf(Ts[0][d][c] + Ts[1][d][c], Ws[d * C_ + c], a);
        y1[((size_t)m * O_ + o) * C_ + c] = a;
    }
}

__global__ __launch_bounds__(256) void fiber_old_kernel(
    const float* __restrict__ y1, const float* __restrict__ rkv,
    const float* __restrict__ bias, float* __restrict__ out)
{
    int idx = blockIdx.x * 256 + threadIdx.x;
    if (idx >= M_ * O_ * C_) return;
    int c = idx & (C_ - 1);
    int p = (idx >> 7) % O_;
    int m = idx / (O_ * C_);
    float a = 0.f;
#pragma unroll
    for (int o = 0; o < O_; ++o)
        a = fmaf(y1[(m * O_ + o) * C_ + c], rkv[(p * O_ + o) * C_ + c], a);
    out[idx] = a * (1.0f / 12.0f) + bias[c];
}

__global__ __launch_bounds__(256) void rot_proj_kernel(
    const float* __restrict__ fkb, const float* __restrict__ Wr,
    float* __restrict__ rk)
{
    int idx = blockIdx.x * 256 + threadIdx.x;
    if (idx >= O_ * O_ * C_) return;
    int c  = idx & (C_ - 1);
    int po = idx >> 7;
    const float* f = fkb + po * D_;
    float acc = 0.f;
#pragma unroll
    for (int d = 0; d < D_; ++d) acc = fmaf(f[d], Wr[d * C_ + c], acc);
    rk[idx] = acc;
}

extern "C" void kernel_launch(void* const* d_in, const int* in_sizes, int n_in,
                              void* d_out, int out_size, void* d_ws, size_t ws_size,
                              hipStream_t stream)
{
    const float* x    = (const float*)d_in[0];  // (1,256,12,128)
    const float* kb   = (const float*)d_in[1];  // (1,256,256,12,32)
    const float* fkb  = (const float*)d_in[2];  // (12,12,32)
    const float* mask = (const float*)d_in[3];  // (1,256)
    const float* Wsp  = (const float*)d_in[4];  // (32,128)
    const float* Wrt  = (const float*)d_in[5];  // (32,128)
    const float* bias = (const float*)d_in[6];  // (128,)
    float* out = (float*)d_out;                 // (1,256,12,128)

    const size_t RK_F   = (size_t)O_ * O_ * C_;            // 18432 floats
    const size_t PART_F = (size_t)S2 * M_ * O_ * C_;       // 6291456 floats
    const size_t G_E    = (size_t)O_ * N_ * C_ * D_;       // 12582912 bf16
    const size_t need   = (RK_F + PART_F) * 4 + G_E * 2;   // ~50.5 MB

    float* rk = (float*)d_ws;

    if (ws_size >= need) {
        float* part = rk + RK_F;
        short* g    = (short*)(part + PART_F);
        prep_kernel<<<N_ * O_ + (O_ * O_ * C_) / 256, 256, 0, stream>>>(
            x, mask, Wsp, fkb, Wrt, g, rk);
        spatial4_kernel<<<dim3(M_ / 64, O_, S2), 256, 0, stream>>>(kb, g, part);
        fiber2_kernel<<<M_, 256, 0, stream>>>(part, rk, bias, out);
    } else {
        float* y1 = rk + RK_F;
        rot_proj_kernel<<<(O_ * O_ * C_ + 255) / 256, 256, 0, stream>>>(fkb, Wrt, rk);
        spatial_old_kernel<<<M_ * O_, 256, 0, stream>>>(x, kb, mask, Wsp, y1);
        fiber_old_kernel<<<(M_ * O_ * C_ + 255) / 256, 256, 0, stream>>>(y1, rk, bias, out);
    }
}

// Round 6
// 71.772 us; speedup vs baseline: 1.2532x; 1.0071x over previous
//
#include <hip/hip_runtime.h>
#include <hip/hip_bf16.h>

// Shapes (fixed by the reference): B=1, M=N=256, O=P=12, C=128, D=32
#define N_ 256
#define M_ 256
#define O_ 12
#define C_ 128
#define D_ 32
#define S2 16     // K-splits of the spatial GEMM (16 n-rows per block)

typedef __attribute__((ext_vector_type(8))) short short8;   // 8 x bf16
typedef __attribute__((ext_vector_type(4))) float floatx4;  // MFMA acc

// async global->LDS DMA, 16B per lane: LDS dst = uniform base + lane*16,
// global src is PER-LANE (m173).
#define GLD16(GSRC, LDST) \
    __builtin_amdgcn_global_load_lds( \
        (const __attribute__((address_space(1))) void*)(GSRC), \
        (__attribute__((address_space(3))) void*)(LDST), 16, 0, 0)

static __device__ __forceinline__ short2 pk2(float a, float b) {
    union { __hip_bfloat162 h; short2 s; } u;
    u.h = __float22bfloat162_rn(make_float2(a, b));  // v_cvt_pk_bf16_f32
    return u.s;
}

static __device__ __forceinline__ short f2bf(float f) {
    unsigned u = __float_as_uint(f);
    unsigned r = u + 0x7FFFu + ((u >> 16) & 1u);  // RNE
    return (short)(r >> 16);
}

// ---- fused prep: g[o][n][c][d] = bf16(x[n,o,c]*mask[n]*Ws[d,c])
//      and       rk[p,o,c] = sum_d fkb[p,o,d]*Wr[d,c]
__global__ __launch_bounds__(256) void prep_kernel(
    const float* __restrict__ x, const float* __restrict__ mask,
    const float* __restrict__ Ws, const float* __restrict__ fkb,
    const float* __restrict__ Wr, short* __restrict__ g,
    float* __restrict__ rk)
{
    const int b = blockIdx.x;
    if (b < N_ * O_) {
        const int n = b / O_;
        const int o = b % O_;
        const int t = threadIdx.x;
        const int c  = t >> 1;
        const int dh = (t & 1) * 16;
        const float xm = x[(n * O_ + o) * C_ + c] * mask[n];
        short8 w0, w1;
#pragma unroll
        for (int i = 0; i < 8; ++i) w0[i] = f2bf(xm * Ws[(dh + i) * C_ + c]);
#pragma unroll
        for (int i = 0; i < 8; ++i) w1[i] = f2bf(xm * Ws[(dh + 8 + i) * C_ + c]);
        short* gp = g + (((size_t)(o * N_ + n)) * C_ + c) * D_ + dh;
        *reinterpret_cast<short8*>(gp)     = w0;
        *reinterpret_cast<short8*>(gp + 8) = w1;
    } else {
        const int idx = (b - N_ * O_) * 256 + threadIdx.x;  // 0..18431
        const int c  = idx & (C_ - 1);
        const int po = idx >> 7;
        const float* f = fkb + po * D_;
        float acc = 0.f;
#pragma unroll
        for (int d = 0; d < D_; ++d) acc = fmaf(f[d], Wr[d * C_ + c], acc);
        rk[idx] = acc;
    }
}

// ---- spatial GEMM: counted-vmcnt triple-buffered DMA pipeline (T3+T4) ---
// Per o: y1[m,c] = sum_{(n,d)} kb[m,n,o,d]*g[o,n,c,d].
// Block: 64 m-rows x 128 c, 16 n-steps (BK=32). 4 waves; each wave stages
// exactly 4 DMA instrs/step (its own A rows + a quarter of B) and computes
// 16 m-rows x 128 c (8 MFMAs/step).
// Pipeline per step: s_waitcnt vmcnt(4) [keep next step's loads in flight
// across the barrier] -> s_barrier -> STAGE(s+2) -> ds_read/cvt/MFMA ->
// s_waitcnt lgkmcnt(0) [WAR safety for the post-barrier overwrite].
__global__ __launch_bounds__(256, 3) void spatial5_kernel(
    const float* __restrict__ kb, const short* __restrict__ g,
    float* __restrict__ part)
{
    const int mt  = blockIdx.x;   // 0..3
    const int o   = blockIdx.y;   // 0..11
    const int sck = blockIdx.z;   // 0..15
    const int t    = threadIdx.x;
    const int lane = t & 63;
    const int wave = t >> 6;
    const int l15  = lane & 15;
    const int lk   = lane >> 4;
    const int m0   = mt * 64;
    const int n0   = sck * (N_ / S2);

    __shared__ __align__(16) float Abuf[3][64 * 32];   // 3 x 8 KB
    __shared__ __align__(16) short Bbuf[3][128 * 32];  // 3 x 8 KB

    // ---- staging constants (each wave: 2 A + 2 B DMA instrs per step)
    const int iA0 = 2 * wave, iA1 = 2 * wave + 1;
    const int arow0 = 8 * iA0 + (lane >> 3);          // rows covered by instr
    const int arow1 = 8 * iA1 + (lane >> 3);
    const int achk  = ((lane & 7) - (lane >> 3)) & 7; // pre-rotated src chunk
    const float* kbA0 = kb + (size_t)(m0 + arow0) * (N_ * O_ * D_)
                           + (size_t)n0 * (O_ * D_) + o * D_ + achk * 4;
    const float* kbA1 = kb + (size_t)(m0 + arow1) * (N_ * O_ * D_)
                           + (size_t)n0 * (O_ * D_) + o * D_ + achk * 4;
    const short* gsl = g + (size_t)o * (N_ * C_ * D_)
                         + (size_t)n0 * (C_ * D_) + lane * 8;

#define STAGE(BUF, S) { \
    const size_t no_ = (size_t)(S) * (O_ * D_); \
    GLD16(kbA0 + no_, &Abuf[BUF][iA0 * 256]); \
    GLD16(kbA1 + no_, &Abuf[BUF][iA1 * 256]); \
    const short* gs_ = gsl + (size_t)(S) * (C_ * D_); \
    GLD16(gs_ + iA0 * 512, &Bbuf[BUF][iA0 * 512]); \
    GLD16(gs_ + iA1 * 512, &Bbuf[BUF][iA1 * 512]); }

    floatx4 acc[8];
#pragma unroll
    for (int cg = 0; cg < 8; ++cg)
#pragma unroll
        for (int q = 0; q < 4; ++q) acc[cg][q] = 0.f;

    const int rloc = wave * 16 + l15;            // A row this lane reads
    const int ja = (2 * lk + rloc) & 7;          // rotated chunk indices
    const int jb = (2 * lk + 1 + rloc) & 7;

    // prologue: 2 steps in flight before first wait
    STAGE(0, 0);
    STAGE(1, 1);

#pragma unroll
    for (int s = 0; s < 16; ++s) {
        // my step-s loads complete; step-(s+1) loads stay in flight
        if (s < 15) asm volatile("s_waitcnt vmcnt(4)" ::: "memory");
        else        asm volatile("s_waitcnt vmcnt(0)" ::: "memory");
        __builtin_amdgcn_s_barrier();   // all waves: step-s data ready; all
                                        // waves done READING buf[(s-1)%3]
        if (s + 2 < 16) STAGE((s + 2) % 3, s + 2);  // overwrite buf[(s-1)%3]

        const int bix = s % 3;
        const floatx4 a0 = *reinterpret_cast<const floatx4*>(
            &Abuf[bix][rloc * 32 + ja * 4]);
        const floatx4 a1 = *reinterpret_cast<const floatx4*>(
            &Abuf[bix][rloc * 32 + jb * 4]);
        union { short8 v; short2 p2[4]; } au;
        au.p2[0] = pk2(a0[0], a0[1]);
        au.p2[1] = pk2(a0[2], a0[3]);
        au.p2[2] = pk2(a1[0], a1[1]);
        au.p2[3] = pk2(a1[2], a1[3]);
#pragma unroll
        for (int cg = 0; cg < 8; ++cg) {
            const short8 bf = *reinterpret_cast<const short8*>(
                &Bbuf[bix][(cg * 16 + l15) * 32 + lk * 8]);
            acc[cg] = __builtin_amdgcn_mfma_f32_16x16x32_bf16(au.v, bf, acc[cg], 0, 0, 0);
        }
        // all my LDS reads RETURNED before crossing the next barrier
        asm volatile("s_waitcnt lgkmcnt(0)" ::: "memory");
    }
#undef STAGE

    // C/D layout: col = lane&15, row = (lane>>4)*4 + reg  [verified round 2]
#pragma unroll
    for (int cg = 0; cg < 8; ++cg) {
        const int c = cg * 16 + l15;
#pragma unroll
        for (int j = 0; j < 4; ++j) {
            const int m = m0 + wave * 16 + lk * 4 + j;
            part[(((size_t)sck * M_ + m) * O_ + o) * C_ + c] = acc[cg][j];
        }
    }
}

// ---- out[m,p,c] = (sum_o (sum_s part[s,m,o,c]) * rk[p,o,c])/12 + bias[c]
__global__ __launch_bounds__(256) void fiber2_kernel(
    const float* __restrict__ part, const float* __restrict__ rkv,
    const float* __restrict__ bias, float* __restrict__ out)
{
    const int m = blockIdx.x;
    const int t = threadIdx.x;
    const int c = t & 127;
    const int half = t >> 7;
    float y1v[O_];
#pragma unroll
    for (int o = 0; o < O_; ++o) {
        float a = 0.f;
#pragma unroll
        for (int s = 0; s < S2; ++s)
            a += part[(((size_t)s * M_ + m) * O_ + o) * C_ + c];
        y1v[o] = a;
    }
#pragma unroll
    for (int pp = 0; pp < O_ / 2; ++pp) {
        const int p = half * (O_ / 2) + pp;
        float a = 0.f;
#pragma unroll
        for (int o = 0; o < O_; ++o)
            a = fmaf(y1v[o], rkv[(p * O_ + o) * C_ + c], a);
        out[((size_t)m * O_ + p) * C_ + c] = a * (1.f / 12.f) + bias[c];
    }
}

// ---------------- fallback (round-1) path, used only if ws is small ------
__global__ __launch_bounds__(256) void spatial_old_kernel(
    const float* __restrict__ x, const float* __restrict__ kb,
    const float* __restrict__ mask, const float* __restrict__ Ws,
    float* __restrict__ y1)
{
    const int bid = blockIdx.x;
    const int m = bid / O_, o = bid % O_;
    const int tid = threadIdx.x;
    const int h = tid >> 7, c = tid & (C_ - 1);
    __shared__ float kbs[2][8][D_];
    __shared__ float msk[N_];
    __shared__ float Ts[2][D_][C_];
    msk[tid] = mask[tid];
    float T[D_];
#pragma unroll
    for (int d = 0; d < D_; ++d) T[d] = 0.f;
    const float* kb_mo = kb + (size_t)m * (N_ * O_ * D_) + o * D_;
    const int j_ld = c >> 4, d_ld = (c & 15) * 2;
    for (int chunk = 0; chunk < 16; ++chunk) {
        const int n0 = h * 128 + chunk * 8;
        __syncthreads();
        float2 v = *reinterpret_cast<const float2*>(
            kb_mo + (size_t)(n0 + j_ld) * (O_ * D_) + d_ld);
        kbs[h][j_ld][d_ld] = v.x;
        kbs[h][j_ld][d_ld + 1] = v.y;
        __syncthreads();
#pragma unroll
        for (int j = 0; j < 8; ++j) {
            const int n = n0 + j;
            const float xv = x[(n * O_ + o) * C_ + c] * msk[n];
#pragma unroll
            for (int d = 0; d < D_; ++d) T[d] = fmaf(kbs[h][j][d], xv, T[d]);
        }
    }
#pragma unroll
    for (int d = 0; d < D_; ++d) Ts[h][d][c] = T[d];
    __syncthreads();
    if (h == 0) {
        float a = 0.f;
#pragma unroll
        for (int d = 0; d < D_; ++d)
            a = fmaf(Ts[0][d][c] + Ts[1][d][c], Ws[d * C_ + c], a);
        y1[((size_t)m * O_ + o) * C_ + c] = a;
    }
}

__global__ __launch_bounds__(256) void fiber_old_kernel(
    const float* __restrict__ y1, const float* __restrict__ rkv,
    const float* __restrict__ bias, float* __restrict__ out)
{
    int idx = blockIdx.x * 256 + threadIdx.x;
    if (idx >= M_ * O_ * C_) return;
    int c = idx & (C_ - 1);
    int p = (idx >> 7) % O_;
    int m = idx / (O_ * C_);
    float a = 0.f;
#pragma unroll
    for (int o = 0; o < O_; ++o)
        a = fmaf(y1[(m * O_ + o) * C_ + c], rkv[(p * O_ + o) * C_ + c], a);
    out[idx] = a * (1.0f / 12.0f) + bias[c];
}

__global__ __launch_bounds__(256) void rot_proj_kernel(
    const float* __restrict__ fkb, const float* __restrict__ Wr,
    float* __restrict__ rk)
{
    int idx = blockIdx.x * 256 + threadIdx.x;
    if (idx >= O_ * O_ * C_) return;
    int c  = idx & (C_ - 1);
    int po = idx >> 7;
    const float* f = fkb + po * D_;
    float acc = 0.f;
#pragma unroll
    for (int d = 0; d < D_; ++d) acc = fmaf(f[d], Wr[d * C_ + c], acc);
    rk[idx] = acc;
}

extern "C" void kernel_launch(void* const* d_in, const int* in_sizes, int n_in,
                              void* d_out, int out_size, void* d_ws, size_t ws_size,
                              hipStream_t stream)
{
    const float* x    = (const float*)d_in[0];  // (1,256,12,128)
    const float* kb   = (const float*)d_in[1];  // (1,256,256,12,32)
    const float* fkb  = (const float*)d_in[2];  // (12,12,32)
    const float* mask = (const float*)d_in[3];  // (1,256)
    const float* Wsp  = (const float*)d_in[4];  // (32,128)
    const float* Wrt  = (const float*)d_in[5];  // (32,128)
    const float* bias = (const float*)d_in[6];  // (128,)
    float* out = (float*)d_out;                 // (1,256,12,128)

    const size_t RK_F   = (size_t)O_ * O_ * C_;            // 18432 floats
    const size_t PART_F = (size_t)S2 * M_ * O_ * C_;       // 6291456 floats
    const size_t G_E    = (size_t)O_ * N_ * C_ * D_;       // 12582912 bf16
    const size_t need   = (RK_F + PART_F) * 4 + G_E * 2;   // ~50.5 MB

    float* rk = (float*)d_ws;

    if (ws_size >= need) {
        float* part = rk + RK_F;
        short* g    = (short*)(part + PART_F);
        prep_kernel<<<N_ * O_ + (O_ * O_ * C_) / 256, 256, 0, stream>>>(
            x, mask, Wsp, fkb, Wrt, g, rk);
        spatial5_kernel<<<dim3(M_ / 64, O_, S2), 256, 0, stream>>>(kb, g, part);
        fiber2_kernel<<<M_, 256, 0, stream>>>(part, rk, bias, out);
    } else {
        float* y1 = rk + RK_F;
        rot_proj_kernel<<<(O_ * O_ * C_ + 255) / 256, 256, 0, stream>>>(fkb, Wrt, rk);
        spatial_old_kernel<<<M_ * O_, 256, 0, stream>>>(x, kb, mask, Wsp, y1);
        fiber_old_kernel<<<(M_ * O_ * C_ + 255) / 256, 256, 0, stream>>>(y1, rk, bias, out);
    }
}

// Round 7
// 43.222 us; speedup vs baseline: 2.0810x; 1.6606x over previous
//
#include <hip/hip_runtime.h>
#include <hip/hip_bf16.h>

// Shapes (fixed by the reference): B=1, M=N=256, O=P=12, C=128, D=32
#define N_ 256
#define M_ 256
#define O_ 12
#define C_ 128
#define D_ 32
#define S2 16          // n-splits (16 n per block)
#define KBROW 393216   // bytes per kb m-row = N*O*D*4

typedef __attribute__((ext_vector_type(8))) short short8;   // 8 x bf16
typedef __attribute__((ext_vector_type(4))) float floatx4;  // MFMA acc

// async global->LDS DMA, 16B/lane: LDS dst = uniform base + lane*16,
// global src is per-lane (m173).
#define GLD16(GSRC, LDST) \
    __builtin_amdgcn_global_load_lds( \
        (const __attribute__((address_space(1))) void*)(GSRC), \
        (__attribute__((address_space(3))) void*)(LDST), 16, 0, 0)

static __device__ __forceinline__ short2 pk2(float a, float b) {
    union { __hip_bfloat162 h; short2 s; } u;
    u.h = __float22bfloat162_rn(make_float2(a, b));  // v_cvt_pk_bf16_f32 RNE
    return u.s;
}

// ---- prep2: xmm[n][o][c] = x[n,o,c]*mask[n]  and  rk[p,o,c] -------------
__global__ __launch_bounds__(256) void prep2_kernel(
    const float* __restrict__ x, const float* __restrict__ mask,
    const float* __restrict__ fkb, const float* __restrict__ Wr,
    float* __restrict__ xmm, float* __restrict__ rk)
{
    const int b = blockIdx.x;
    const int t = threadIdx.x;
    if (b < 1536) {                       // 1536*256 = 393216 = N*O*C
        const int idx = b * 256 + t;
        const int n = idx / (O_ * C_);
        xmm[idx] = x[idx] * mask[n];
    } else {
        const int idx = (b - 1536) * 256 + t;   // < 18432 = O*O*C
        const int c  = idx & (C_ - 1);
        const int po = idx >> 7;
        const float* f = fkb + po * D_;
        float acc = 0.f;
#pragma unroll
        for (int d = 0; d < D_; ++d) acc = fmaf(f[d], Wr[d * C_ + c], acc);
        rk[idx] = acc;
    }
}

// ---- spatial6: contiguous-kb streaming, wave-per-o, B built on the fly --
// part[m][s][o][c] += sum over the block's 16 n of kb x (xmm*Ws).
// Block (mt, sck): 16 m-rows x 16 n, 768 threads = 12 waves (wave w = o).
// Per n-step: DMA full rows kb[m0+r][n][0..1536B) -> LDS (24 KB), swizzled
// via pre-swizzled SOURCE (LDS dst linear, rule 21). NBUF=4, counted
// vmcnt(10): exactly the prefetched stage + trailing x-loads stay in flight.
__global__ __launch_bounds__(768, 3) void spatial6_kernel(
    const float* __restrict__ kb, const float* __restrict__ xmm,
    const float* __restrict__ Ws, float* __restrict__ part)
{
    const int mt  = blockIdx.x;   // 0..15
    const int sck = blockIdx.y;   // 0..15
    const int t = threadIdx.x;
    const int lane = t & 63;
    const int w = t >> 6;         // wave = o (0..11)
    const int l15 = lane & 15;
    const int lk  = lane >> 4;
    const int m0 = mt * 16;
    const int n0 = sck * 16;

    __shared__ __align__(16) char Abuf[4 * 24576];   // 96 KB

    // staging: wave w covers 16B-slots j in [w*128, w*128+128) of the
    // 1536-slot [16 r][96 s] step tile; slot (r,s) holds logical (r, s^(r&7)).
    const int j0 = w * 128 + lane;
    const int j1 = j0 + 64;
    const int r0 = j0 / 96, s0j = j0 % 96;
    const int r1 = j1 / 96, s1j = j1 % 96;
    const char* kbc = (const char*)kb;
    const char* src0 = kbc + (size_t)(m0 + r0) * KBROW + (size_t)n0 * 1536
                       + (size_t)((s0j ^ (r0 & 7)) * 16);
    const char* src1 = kbc + (size_t)(m0 + r1) * KBROW + (size_t)n0 * 1536
                       + (size_t)((s1j ^ (r1 & 7)) * 16);
    char* dst0 = Abuf + w * 2048;
    char* dst1 = Abuf + w * 2048 + 1024;

#define STAGE(BIX, S) { \
    GLD16(src0 + (size_t)(S) * 1536, dst0 + (BIX) * 24576); \
    GLD16(src1 + (size_t)(S) * 1536, dst1 + (BIX) * 24576); }

    // per-lane Ws fragment (held in VGPRs): wsr[cg][i] = Ws[lk*8+i][cg*16+l15]
    float wsr[8][8];
#pragma unroll
    for (int cg = 0; cg < 8; ++cg)
#pragma unroll
        for (int i = 0; i < 8; ++i)
            wsr[cg][i] = Ws[(lk * 8 + i) * C_ + cg * 16 + l15];

    // A-read offsets: logical slot q = w*8 + lk*2 + {0,1} of row r=l15
    const int off0 = l15 * 1536 + (((w * 8 + lk * 2    ) ^ (l15 & 7)) * 16);
    const int off1 = l15 * 1536 + (((w * 8 + lk * 2 + 1) ^ (l15 & 7)) * 16);

    const float* xb = xmm + ((size_t)n0 * O_ + w) * C_ + l15;

    floatx4 acc[8];
#pragma unroll
    for (int cg = 0; cg < 8; ++cg)
#pragma unroll
        for (int q = 0; q < 4; ++q) acc[cg][q] = 0.f;

    STAGE(0, 0);
    STAGE(1, 1);

    float xvA[8], xvB[8];
#pragma unroll
    for (int cg = 0; cg < 8; ++cg) xvA[cg] = xb[cg * 16];   // x for s=0

    // Per phase: vmcnt(10) guarantees stage-s landed (FIFO: at most
    // [stage s(2), stage s+1(2), x(8)] = 12 outstanding; 10 retires stage-s
    // only, never blocks on the younger x / prefetch stage).
#define PHASE(S, BIX, XC, XN) { \
    asm volatile("s_waitcnt vmcnt(10)" ::: "memory"); \
    __builtin_amdgcn_s_barrier(); \
    if ((S) + 2 < 16) STAGE(((BIX) + 2) & 3, (S) + 2); \
    const char* ab_ = Abuf + (BIX) * 24576; \
    const floatx4 a0_ = *(const floatx4*)(ab_ + off0); \
    const floatx4 a1_ = *(const floatx4*)(ab_ + off1); \
    union { short8 v; short2 p2[4]; } au_; \
    au_.p2[0] = pk2(a0_[0], a0_[1]); au_.p2[1] = pk2(a0_[2], a0_[3]); \
    au_.p2[2] = pk2(a1_[0], a1_[1]); au_.p2[3] = pk2(a1_[2], a1_[3]); \
    _Pragma("unroll") \
    for (int cg = 0; cg < 8; ++cg) { \
        union { short8 v; short2 p2[4]; } bu_; \
        bu_.p2[0] = pk2(XC[cg] * wsr[cg][0], XC[cg] * wsr[cg][1]); \
        bu_.p2[1] = pk2(XC[cg] * wsr[cg][2], XC[cg] * wsr[cg][3]); \
        bu_.p2[2] = pk2(XC[cg] * wsr[cg][4], XC[cg] * wsr[cg][5]); \
        bu_.p2[3] = pk2(XC[cg] * wsr[cg][6], XC[cg] * wsr[cg][7]); \
        acc[cg] = __builtin_amdgcn_mfma_f32_16x16x32_bf16(au_.v, bu_.v, acc[cg], 0, 0, 0); \
    } \
    if ((S) + 1 < 16) { \
        _Pragma("unroll") \
        for (int cg = 0; cg < 8; ++cg) \
            XN[cg] = xb[(size_t)((S) + 1) * (O_ * C_) + cg * 16]; \
    } }

    for (int sb = 0; sb < 16; sb += 4) {
        PHASE(sb + 0, 0, xvA, xvB)
        PHASE(sb + 1, 1, xvB, xvA)
        PHASE(sb + 2, 2, xvA, xvB)
        PHASE(sb + 3, 3, xvB, xvA)
    }
#undef PHASE
#undef STAGE

    // C/D: col = lane&15, row = (lane>>4)*4 + reg  [verified rounds 2-5]
#pragma unroll
    for (int cg = 0; cg < 8; ++cg) {
        const int c = cg * 16 + l15;
#pragma unroll
        for (int j = 0; j < 4; ++j) {
            const int m = m0 + lk * 4 + j;
            part[(((size_t)m * S2 + sck) * O_ + w) * C_ + c] = acc[cg][j];
        }
    }
}

// ---- fiber3: out[m,p,c] = (sum_o (sum_s part[m,s,o,c]) * rk[p,o,c])/12 + b
__global__ __launch_bounds__(256) void fiber3_kernel(
    const float* __restrict__ part, const float* __restrict__ rkv,
    const float* __restrict__ bias, float* __restrict__ out)
{
    const int m = blockIdx.x;
    const int t = threadIdx.x;
    const int c = t & 127;
    const int half = t >> 7;
    float y1v[O_];
#pragma unroll
    for (int o = 0; o < O_; ++o) {
        float a = 0.f;
#pragma unroll
        for (int s = 0; s < S2; ++s)
            a += part[(((size_t)m * S2 + s) * O_ + o) * C_ + c];
        y1v[o] = a;
    }
#pragma unroll
    for (int pp = 0; pp < O_ / 2; ++pp) {
        const int p = half * (O_ / 2) + pp;
        float a = 0.f;
#pragma unroll
        for (int o = 0; o < O_; ++o)
            a = fmaf(y1v[o], rkv[(p * O_ + o) * C_ + c], a);
        out[((size_t)m * O_ + p) * C_ + c] = a * (1.f / 12.f) + bias[c];
    }
}

// ---------------- fallback (round-1) path, used only if ws is small ------
__global__ __launch_bounds__(256) void spatial_old_kernel(
    const float* __restrict__ x, const float* __restrict__ kb,
    const float* __restrict__ mask, const float* __restrict__ Ws,
    float* __restrict__ y1)
{
    const int bid = blockIdx.x;
    const int m = bid / O_, o = bid % O_;
    const int tid = threadIdx.x;
    const int h = tid >> 7, c = tid & (C_ - 1);
    __shared__ float kbs[2][8][D_];
    __shared__ float msk[N_];
    __shared__ float Ts[2][D_][C_];
    msk[tid] = mask[tid];
    float T[D_];
#pragma unroll
    for (int d = 0; d < D_; ++d) T[d] = 0.f;
    const float* kb_mo = kb + (size_t)m * (N_ * O_ * D_) + o * D_;
    const int j_ld = c >> 4, d_ld = (c & 15) * 2;
    for (int chunk = 0; chunk < 16; ++chunk) {
        const int n0 = h * 128 + chunk * 8;
        __syncthreads();
        float2 v = *reinterpret_cast<const float2*>(
            kb_mo + (size_t)(n0 + j_ld) * (O_ * D_) + d_ld);
        kbs[h][j_ld][d_ld] = v.x;
        kbs[h][j_ld][d_ld + 1] = v.y;
        __syncthreads();
#pragma unroll
        for (int j = 0; j < 8; ++j) {
            const int n = n0 + j;
            const float xv = x[(n * O_ + o) * C_ + c] * msk[n];
#pragma unroll
            for (int d = 0; d < D_; ++d) T[d] = fmaf(kbs[h][j][d], xv, T[d]);
        }
    }
#pragma unroll
    for (int d = 0; d < D_; ++d) Ts[h][d][c] = T[d];
    __syncthreads();
    if (h == 0) {
        float a = 0.f;
#pragma unroll
        for (int d = 0; d < D_; ++d)
            a = fmaf(Ts[0][d][c] + Ts[1][d][c], Ws[d * C_ + c], a);
        y1[((size_t)m * O_ + o) * C_ + c] = a;
    }
}

__global__ __launch_bounds__(256) void fiber_old_kernel(
    const float* __restrict__ y1, const float* __restrict__ rkv,
    const float* __restrict__ bias, float* __restrict__ out)
{
    int idx = blockIdx.x * 256 + threadIdx.x;
    if (idx >= M_ * O_ * C_) return;
    int c = idx & (C_ - 1);
    int p = (idx >> 7) % O_;
    int m = idx / (O_ * C_);
    float a = 0.f;
#pragma unroll
    for (int o = 0; o < O_; ++o)
        a = fmaf(y1[(m * O_ + o) * C_ + c], rkv[(p * O_ + o) * C_ + c], a);
    out[idx] = a * (1.0f / 12.0f) + bias[c];
}

__global__ __launch_bounds__(256) void rot_proj_kernel(
    const float* __restrict__ fkb, const float* __restrict__ Wr,
    float* __restrict__ rk)
{
    int idx = blockIdx.x * 256 + threadIdx.x;
    if (idx >= O_ * O_ * C_) return;
    int c  = idx & (C_ - 1);
    int po = idx >> 7;
    const float* f = fkb + po * D_;
    float acc = 0.f;
#pragma unroll
    for (int d = 0; d < D_; ++d) acc = fmaf(f[d], Wr[d * C_ + c], acc);
    rk[idx] = acc;
}

extern "C" void kernel_launch(void* const* d_in, const int* in_sizes, int n_in,
                              void* d_out, int out_size, void* d_ws, size_t ws_size,
                              hipStream_t stream)
{
    const float* x    = (const float*)d_in[0];  // (1,256,12,128)
    const float* kb   = (const float*)d_in[1];  // (1,256,256,12,32)
    const float* fkb  = (const float*)d_in[2];  // (12,12,32)
    const float* mask = (const float*)d_in[3];  // (1,256)
    const float* Wsp  = (const float*)d_in[4];  // (32,128)
    const float* Wrt  = (const float*)d_in[5];  // (32,128)
    const float* bias = (const float*)d_in[6];  // (128,)
    float* out = (float*)d_out;                 // (1,256,12,128)

    const size_t RK_F   = (size_t)O_ * O_ * C_;        // 18432 floats
    const size_t PART_F = (size_t)M_ * S2 * O_ * C_;   // 6291456 floats
    const size_t XMM_F  = (size_t)N_ * O_ * C_;        // 393216 floats
    const size_t need   = (RK_F + PART_F + XMM_F) * 4; // ~26.8 MB

    float* rk = (float*)d_ws;

    if (ws_size >= need) {
        float* part = rk + RK_F;
        float* xmm  = part + PART_F;
        prep2_kernel<<<1536 + (O_ * O_ * C_) / 256, 256, 0, stream>>>(
            x, mask, fkb, Wrt, xmm, rk);
        spatial6_kernel<<<dim3(16, 16), 768, 0, stream>>>(kb, xmm, Wsp, part);
        fiber3_kernel<<<M_, 256, 0, stream>>>(part, rk, bias, out);
    } else {
        float* y1 = rk + RK_F;
        rot_proj_kernel<<<(O_ * O_ * C_ + 255) / 256, 256, 0, stream>>>(fkb, Wrt, rk);
        spatial_old_kernel<<<M_ * O_, 256, 0, stream>>>(x, kb, mask, Wsp, y1);
        fiber_old_kernel<<<(M_ * O_ * C_ + 255) / 256, 256, 0, stream>>>(y1, rk, bias, out);
    }
}